// Round 8
// baseline (4759.610 us; speedup 1.0000x reference)
//
#include <hip/hip_runtime.h>

#define NTIME   101
#define BATCH   4096
#define DIM     64
#define WIDTH   256
#define TB      16
#define NTHREADS 1024
#define AST     264   // A-split LDS row stride in halves: 528 B, 16B-aligned
#define SPS     68    // sP row stride in floats: breaks 4-way bank conflict on partial writes

// Tsit5 coefficients
#define A21 0.161f
#define A31 (-0.008480655492356989f)
#define A32 0.335480655492357f
#define A41 2.8971530571054935f
#define A42 (-6.359448489975075f)
#define A43 4.3622954328695815f
#define A51 5.325864828439257f
#define A52 (-11.748883564062828f)
#define A53 7.4955393428898365f
#define A54 (-0.09249506636175525f)
#define A61 5.86145544294642f
#define A62 (-12.92096931784711f)
#define A63 8.159367898576159f
#define A64 (-0.071584973281401f)
#define A65 (-0.028269050394068383f)
#define B1 0.09646076681806523f
#define B2 0.01f
#define B3 0.4798896504144996f
#define B4 1.379008574103742f
#define B5 (-3.290069515436081f)
#define B6 2.324710524099774f

typedef float  floatx4 __attribute__((ext_vector_type(4)));
typedef _Float16 halfx8 __attribute__((ext_vector_type(8)));

// packed-weight segment offsets in d_ws (in _Float16 elements)
#define L0S1 0
#define L0S2 16384
#define L1S1 32768
#define L1S2 98304
#define L2S1 163840
#define L2S2 229376
#define L3S1 294912
#define L3S2 311296

__device__ __forceinline__ float fast_tanh(float x) {
    float e = __expf(2.0f * x);
    return 1.0f - 2.0f / (e + 1.0f);
}

// lgkm-only barrier: all cross-wave communication is through LDS (sA/sP/sK/sY);
// the per-wave sB staging slots are private, so global_load_lds prefetches
// legally stay in flight ACROSS this barrier (T4). R5-verified winner.
__device__ __forceinline__ void bar_lds() {
    asm volatile("s_waitcnt lgkmcnt(0)\n\ts_barrier" ::: "memory");
}

// Split fp32 weights into scaled fp16 pairs, pack into MFMA B-fragment layout.
// Fragment block fb = nt*(K/32)+kc: 64 lanes x 8 halves; lane = q*16 + (n&15)
// supplies B[k = kc*32 + q*8 + j][n].
__global__ void pack_weights(const float* __restrict__ W0, const float* __restrict__ W1,
                             const float* __restrict__ W2, const float* __restrict__ W3,
                             _Float16* __restrict__ ws)
{
    int idx = blockIdx.x * 256 + threadIdx.x;
    const float* W; int K, N, e; size_t d1, d2;
    if (idx < 16384)       { W = W0; K = 64;  N = 256; e = idx;          d1 = L0S1; d2 = L0S2; }
    else if (idx < 81920)  { W = W1; K = 256; N = 256; e = idx - 16384;  d1 = L1S1; d2 = L1S2; }
    else if (idx < 147456) { W = W2; K = 256; N = 256; e = idx - 81920;  d1 = L2S1; d2 = L2S2; }
    else if (idx < 163840) { W = W3; K = 256; N = 64;  e = idx - 147456; d1 = L3S1; d2 = L3S2; }
    else return;
    int k = e / N, n = e % N;
    float w = W[e];
    _Float16 h1 = (_Float16)w;
    _Float16 h2 = (_Float16)((w - (float)h1) * 4096.0f);
    int kc = k >> 5, q = (k >> 3) & 3, j = k & 7, nt = n >> 4, nc = n & 15;
    size_t off = ((size_t)((nt * (K / 32) + kc) * 64 + q * 16 + nc)) * 8 + j;
    ws[d1 + off] = h1;
    ws[d2 + off] = h2;
}

// Issue async global->LDS staging of one B chunk (both planes) into this wave's
// slot buffer. LDS dest = wave-uniform base + lane*16 (HW rule); global source
// is per-lane. Zero VGPR data cost -- the depth-2 pipeline the 64-VGPR cap
// forbids in registers (R1-R4).
__device__ __forceinline__ void stage_b(const _Float16* __restrict__ g1,
                                        const _Float16* __restrict__ g2,
                                        _Float16* slot, int fb, int lane)
{
    const _Float16* s1 = g1 + (((size_t)fb) * 64 + lane) * 8;
    const _Float16* s2 = g2 + (((size_t)fb) * 64 + lane) * 8;
    __builtin_amdgcn_global_load_lds(
        (const __attribute__((address_space(1))) void*)s1,
        (__attribute__((address_space(3))) void*)slot, 16, 0, 0);
    __builtin_amdgcn_global_load_lds(
        (const __attribute__((address_space(1))) void*)s2,
        (__attribute__((address_space(3))) void*)(slot + 512), 16, 0, 0);
}

// K-loop with LDS-staged B, depth-2, counted vmcnt (T3/T4).
// Contract: chunks c0,c1 already issued into slot buf0,buf1 (by the previous
// phase's epilogue, flying across the lgkm-only barrier). In-loop: consume ci
// from buf[i&1], then reissue c_{i+2} into the same buf (data was consumed --
// lgkm-waited before the MFMAs). vmcnt retires in order, so vmcnt(2) at iter
// top == "ci arrived"; out-stores are younger and never block counted waits.
// A-reads stay register-pipelined one chunk ahead (LDS latency hiding).
template<int KCNT>
__device__ __forceinline__ void mfma_staged(const _Float16* __restrict__ pA1,
                                            const _Float16* __restrict__ pA2,
                                            const _Float16* __restrict__ g1,
                                            const _Float16* __restrict__ g2,
                                            _Float16* slot, int fbBase, int kcStart,
                                            int lane,
                                            floatx4& acc1o, floatx4& acc2o)
{
    const int m = lane & 15, q = lane >> 4;
    floatx4 acc1 = (floatx4)0.0f, acc2 = (floatx4)0.0f;
    halfx8 va1[2], va2[2];

    const int aOff0 = m * AST + kcStart * 32 + q * 8;
    va1[0] = *(const halfx8*)(pA1 + aOff0);
    va2[0] = *(const halfx8*)(pA2 + aOff0);

    #pragma unroll
    for (int i = 0; i < KCNT; ++i) {
        const int cur = i & 1, nxt = cur ^ 1;
        if (i + 1 < KCNT) asm volatile("s_waitcnt vmcnt(2)" ::: "memory");
        else              asm volatile("s_waitcnt vmcnt(0)" ::: "memory");
        const _Float16* bs = slot + cur * 1024;
        halfx8 vb1 = *(const halfx8*)(bs + lane * 8);
        halfx8 vb2 = *(const halfx8*)(bs + 512 + lane * 8);
        if (i + 1 < KCNT) {
            const int aOff = m * AST + (kcStart + i + 1) * 32 + q * 8;
            va1[nxt] = *(const halfx8*)(pA1 + aOff);
            va2[nxt] = *(const halfx8*)(pA2 + aOff);
        }
        acc1 = __builtin_amdgcn_mfma_f32_16x16x32_f16(va1[cur], vb1, acc1, 0, 0, 0);
        acc2 = __builtin_amdgcn_mfma_f32_16x16x32_f16(va1[cur], vb2, acc2, 0, 0, 0);
        acc2 = __builtin_amdgcn_mfma_f32_16x16x32_f16(va2[cur], vb1, acc2, 0, 0, 0);
        if (i + 2 < KCNT)
            stage_b(g1, g2, slot + cur * 1024, fbBase + i + 2, lane);
    }
    acc1o = acc1; acc2o = acc2;
}

// Hidden-layer epilogue: combine splits, bias, tanh, write fp16 split planes.
__device__ __forceinline__ void hidden_epi(floatx4 a1, floatx4 a2,
                                           const float* __restrict__ bias,
                                           _Float16* __restrict__ o1,
                                           _Float16* __restrict__ o2,
                                           int w, int lane)
{
    const int m = lane & 15, q = lane >> 4;
    const int col = (w << 4) + m;
    const float bb = bias[col];
    #pragma unroll
    for (int v = 0; v < 4; ++v) {
        float val = fast_tanh(a1[v] + a2[v] * (1.0f / 4096.0f) + bb);
        _Float16 h1 = (_Float16)val;
        _Float16 h2 = (_Float16)((val - (float)h1) * 4096.0f);
        const int idx = (q * 4 + v) * AST + col;   // m89-verified C/D mapping
        o1[idx] = h1;
        o2[idx] = h2;
    }
}

// R8 = R7 structure with B-streaming converted to depth-2 global_load_lds
// staging (cW0 dropped to make room for sB). Phase-start L2 latency is fully
// hidden: next phase's chunks 0,1 are issued BEFORE the lgkm-only barrier and
// stay in flight across it. Per-chunk latency is LDS-read (~120cy) instead of
// L2 (~200-500cy), with counted vmcnt(2) never draining the queue mid-phase.
__global__ void __launch_bounds__(NTHREADS)
ode_kernel(const float* __restrict__ ts, const float* __restrict__ y0,
           const float* __restrict__ b0, const float* __restrict__ b1,
           const float* __restrict__ b2, const float* __restrict__ b3,
           const _Float16* __restrict__ ws, float* __restrict__ out)
{
    // parity-0 / parity-1 A-split buffers
    __shared__ __align__(16) _Float16 sA1[2][TB * AST];
    __shared__ __align__(16) _Float16 sA2[2][TB * AST];
    // per-wave B staging: 16 waves x (2 bufs x 2 planes x 512 halves) = 64 KB
    __shared__ __align__(16) _Float16 sB[16 * 2048];
    __shared__ __align__(16) float sK[5][TB * DIM];
    __shared__ __align__(16) float sY[TB * DIM];
    __shared__ __align__(16) float sP[4][TB * SPS];
    __shared__ __align__(16) float sBias[832];

    const int tid  = threadIdx.x;
    const int lane = tid & 63;
    const int w    = tid >> 6;
    const long base = (long)blockIdx.x * (TB * DIM);
    const int c = tid & 63;       // element column (feature)
    const int r = tid >> 6;       // element row (batch row within tile)
    _Float16* slot = sB + w * 2048;   // this wave's staging slot (private)
    const int nt = w & 3, kg = w >> 2;

    if (tid < 832) {
        float v;
        if (tid < 256)      v = b0[tid];
        else if (tid < 512) v = b1[tid - 256];
        else if (tid < 768) v = b2[tid - 512];
        else                v = b3[tid - 768];
        sBias[tid] = v;
    }
    {
        float v = y0[base + tid];
        sY[tid] = v;
        __builtin_nontemporal_store(v, &out[base + tid]);
        _Float16 h1 = (_Float16)v;
        _Float16 h2 = (_Float16)((v - (float)h1) * 4096.0f);
        sA1[0][r * AST + c] = h1;
        sA2[0][r * AST + c] = h2;
    }
    __syncthreads();

    // kick off the pipeline: L0 chunks 0,1 of the first stage
    stage_b(ws + L0S1, ws + L0S2, slot,        w * 2,     lane);
    stage_b(ws + L0S1, ws + L0S2, slot + 1024, w * 2 + 1, lane);

    const int r68 = r * SPS + c;   // padded sP index for the elementwise phase

    for (int t = 0; t < NTIME - 1; ++t) {
        const float h = ts[t + 1] - ts[t];

        #pragma unroll 1
        for (int s = 0; s < 6; ++s) {
            floatx4 a1, a2;
            // L0: parity 0 -> parity 1
            mfma_staged<2>(sA1[0], sA2[0], ws + L0S1, ws + L0S2, slot,
                           w * 2, 0, lane, a1, a2);
            stage_b(ws + L1S1, ws + L1S2, slot,        w * 8,     lane);
            stage_b(ws + L1S1, ws + L1S2, slot + 1024, w * 8 + 1, lane);
            hidden_epi(a1, a2, sBias + 0, sA1[1], sA2[1], w, lane);
            bar_lds();
            // L1: parity 1 -> parity 0
            mfma_staged<8>(sA1[1], sA2[1], ws + L1S1, ws + L1S2, slot,
                           w * 8, 0, lane, a1, a2);
            stage_b(ws + L2S1, ws + L2S2, slot,        w * 8,     lane);
            stage_b(ws + L2S1, ws + L2S2, slot + 1024, w * 8 + 1, lane);
            hidden_epi(a1, a2, sBias + 256, sA1[0], sA2[0], w, lane);
            bar_lds();
            // L2: parity 0 -> parity 1
            mfma_staged<8>(sA1[0], sA2[0], ws + L2S1, ws + L2S2, slot,
                           w * 8, 0, lane, a1, a2);
            stage_b(ws + L3S1, ws + L3S2, slot,        nt * 8 + kg * 2,     lane);
            stage_b(ws + L3S1, ws + L3S2, slot + 1024, nt * 8 + kg * 2 + 1, lane);
            hidden_epi(a1, a2, sBias + 512, sA1[1], sA2[1], w, lane);
            bar_lds();
            // L3: parity 1 -> partials in sP (4-way K-split across wave groups)
            {
                mfma_staged<2>(sA1[1], sA2[1], ws + L3S1, ws + L3S2, slot,
                               nt * 8 + kg * 2, kg * 2, lane, a1, a2);
                // prefetch next stage's L0 chunks (flies across both barriers)
                stage_b(ws + L0S1, ws + L0S2, slot,        w * 2,     lane);
                stage_b(ws + L0S1, ws + L0S2, slot + 1024, w * 2 + 1, lane);
                const int m = lane & 15, q = lane >> 4;
                #pragma unroll
                for (int v = 0; v < 4; ++v)
                    sP[kg][(q * 4 + v) * SPS + nt * 16 + m]
                        = a1[v] + a2[v] * (1.0f / 4096.0f);
            }
            bar_lds();

            // element-wise: reduce partials -> k_s, form next stage input (or y update)
            float kv = sP[0][r68] + sP[1][r68] + sP[2][r68] + sP[3][r68]
                     + sBias[768 + c];
            float v;
            if (s == 0) {
                sK[0][tid] = kv;
                v = fmaf(h, A21 * kv, sY[tid]);
            } else if (s == 1) {
                sK[1][tid] = kv;
                v = fmaf(h, fmaf(A31, sK[0][tid], A32 * kv), sY[tid]);
            } else if (s == 2) {
                sK[2][tid] = kv;
                float sum = A41 * sK[0][tid] + A42 * sK[1][tid] + A43 * kv;
                v = fmaf(h, sum, sY[tid]);
            } else if (s == 3) {
                sK[3][tid] = kv;
                float sum = A51 * sK[0][tid] + A52 * sK[1][tid] + A53 * sK[2][tid] + A54 * kv;
                v = fmaf(h, sum, sY[tid]);
            } else if (s == 4) {
                sK[4][tid] = kv;
                float sum = A61 * sK[0][tid] + A62 * sK[1][tid] + A63 * sK[2][tid]
                          + A64 * sK[3][tid] + A65 * kv;
                v = fmaf(h, sum, sY[tid]);
            } else {
                float sum = B1 * sK[0][tid] + B2 * sK[1][tid] + B3 * sK[2][tid]
                          + B4 * sK[3][tid] + B5 * sK[4][tid] + B6 * kv;
                v = fmaf(h, sum, sY[tid]);
                sY[tid] = v;
                __builtin_nontemporal_store(v, &out[(long)(t + 1) * (BATCH * DIM) + base + tid]);
            }
            _Float16 h1 = (_Float16)v;
            _Float16 h2 = (_Float16)((v - (float)h1) * 4096.0f);
            sA1[0][r * AST + c] = h1;
            sA2[0][r * AST + c] = h2;
            bar_lds();
        }
    }
}

extern "C" void kernel_launch(void* const* d_in, const int* in_sizes, int n_in,
                              void* d_out, int out_size, void* d_ws, size_t ws_size,
                              hipStream_t stream) {
    (void)in_sizes; (void)n_in; (void)ws_size; (void)out_size;
    const float* ts = (const float*)d_in[0];
    const float* y0 = (const float*)d_in[1];
    const float* W0 = (const float*)d_in[2];
    const float* b0 = (const float*)d_in[3];
    const float* W1 = (const float*)d_in[4];
    const float* b1 = (const float*)d_in[5];
    const float* W2 = (const float*)d_in[6];
    const float* b2 = (const float*)d_in[7];
    const float* W3 = (const float*)d_in[8];
    const float* b3 = (const float*)d_in[9];
    _Float16* ws = (_Float16*)d_ws;
    float* out = (float*)d_out;

    hipLaunchKernelGGL(pack_weights, dim3(640), dim3(256), 0, stream, W0, W1, W2, W3, ws);
    hipLaunchKernelGGL(ode_kernel, dim3(BATCH / TB), dim3(NTHREADS), 0, stream,
                       ts, y0, b0, b1, b2, b3, ws, out);
}

// Round 9
// 4070.074 us; speedup vs baseline: 1.1694x; 1.1694x over previous
//
#include <hip/hip_runtime.h>

#define NTIME   101
#define BATCH   4096
#define DIM     64
#define WIDTH   256
#define TB      16
#define NTHREADS 1024
#define AST     264   // A-split LDS row stride in halves: 528 B, 16B-aligned
#define SPS     68    // sP row stride in floats: breaks 4-way bank conflict on partial writes

// Tsit5 coefficients
#define A21 0.161f
#define A31 (-0.008480655492356989f)
#define A32 0.335480655492357f
#define A41 2.8971530571054935f
#define A42 (-6.359448489975075f)
#define A43 4.3622954328695815f
#define A51 5.325864828439257f
#define A52 (-11.748883564062828f)
#define A53 7.4955393428898365f
#define A54 (-0.09249506636175525f)
#define A61 5.86145544294642f
#define A62 (-12.92096931784711f)
#define A63 8.159367898576159f
#define A64 (-0.071584973281401f)
#define A65 (-0.028269050394068383f)
#define B1 0.09646076681806523f
#define B2 0.01f
#define B3 0.4798896504144996f
#define B4 1.379008574103742f
#define B5 (-3.290069515436081f)
#define B6 2.324710524099774f

typedef float  floatx4 __attribute__((ext_vector_type(4)));
typedef _Float16 halfx8 __attribute__((ext_vector_type(8)));

// packed-weight segment offsets in d_ws (in _Float16 elements)
#define L0S1 0
#define L0S2 16384
#define L1S1 32768
#define L1S2 98304
#define L2S1 163840
#define L2S2 229376
#define L3S1 294912
#define L3S2 311296

__device__ __forceinline__ float fast_tanh(float x) {
    float e = __expf(2.0f * x);
    return 1.0f - 2.0f / (e + 1.0f);
}

// lgkm-only barrier: all cross-wave communication is through LDS; global loads
// (B preloads) and nontemporal out-stores legally stay in flight across it.
__device__ __forceinline__ void bar_lds() {
    asm volatile("s_waitcnt lgkmcnt(0)\n\ts_barrier" ::: "memory");
}

// Split fp32 weights into scaled fp16 pairs, pack into MFMA B-fragment layout.
__global__ void pack_weights(const float* __restrict__ W0, const float* __restrict__ W1,
                             const float* __restrict__ W2, const float* __restrict__ W3,
                             _Float16* __restrict__ ws)
{
    int idx = blockIdx.x * 256 + threadIdx.x;
    const float* W; int K, N, e; size_t d1, d2;
    if (idx < 16384)       { W = W0; K = 64;  N = 256; e = idx;          d1 = L0S1; d2 = L0S2; }
    else if (idx < 81920)  { W = W1; K = 256; N = 256; e = idx - 16384;  d1 = L1S1; d2 = L1S2; }
    else if (idx < 147456) { W = W2; K = 256; N = 256; e = idx - 81920;  d1 = L2S1; d2 = L2S2; }
    else if (idx < 163840) { W = W3; K = 256; N = 64;  e = idx - 147456; d1 = L3S1; d2 = L3S2; }
    else return;
    int k = e / N, n = e % N;
    float w = W[e];
    _Float16 h1 = (_Float16)w;
    _Float16 h2 = (_Float16)((w - (float)h1) * 4096.0f);
    int kc = k >> 5, q = (k >> 3) & 3, j = k & 7, nt = n >> 4, nc = n & 15;
    size_t off = ((size_t)((nt * (K / 32) + kc) * 64 + q * 16 + nc)) * 8 + j;
    ws[d1 + off] = h1;
    ws[d2 + off] = h2;
}

// --- sA swizzle (R9) ---------------------------------------------------------
// 4 rows apart in sA share banks (4*AST*2B = 2112B == 64B mod 128B), making the
// hidden_epi scalar-half writes 4-way conflicted (q=0/2 and q=1/3 collide).
// Fix: XOR the in-row column by ((row>>2)&3)<<3 on BOTH sides:
//   write:  col_store = col ^ (q<<3)            (row = q*4+v  ->  row>>2 == q)
//   read:   lane (m,q) uses q' = q ^ ((m>>2)&3) (row == m)
// Bijective per row; write banks become fully disjoint across q-groups (2-way
// even/odd-m word sharing only = free); A-read bank distribution is unchanged
// as a multiset (q' is a bijection of q per m) -> stays throughput-optimal.
// -----------------------------------------------------------------------------

__device__ __forceinline__ void load_b(const _Float16* __restrict__ g1,
                                       const _Float16* __restrict__ g2,
                                       int fb, int lane, halfx8& o1, halfx8& o2) {
    const size_t f = ((size_t)fb * 64 + lane) * 8;
    o1 = *(const halfx8*)(g1 + f);
    o2 = *(const halfx8*)(g2 + f);
}

// K-loop, chunk-0 B PRELOADED by the previous phase (8 VGPRs across one
// barrier; latency hides under the prior epilogue + barrier). Chunks 1.. are
// depth-1 pipelined as in R0/R7. Plain loads only -- compiler-managed waits
// (no R8-style manual vmcnt; no LDS staging).
template<int KCNT>
__device__ __forceinline__ void mfma_run_pre(const _Float16* __restrict__ pA1,
                                             const _Float16* __restrict__ pA2,
                                             const _Float16* __restrict__ B1g,
                                             const _Float16* __restrict__ B2g,
                                             int fbBase, int kcStart, int lane,
                                             halfx8 pb1, halfx8 pb2,
                                             floatx4& acc1o, floatx4& acc2o)
{
    const int m = lane & 15, q = lane >> 4;
    const int qs = (q ^ ((m >> 2) & 3)) * 8;   // swizzled in-row k-offset
    floatx4 acc1 = (floatx4)0.0f, acc2 = (floatx4)0.0f;
    halfx8 va1[2], va2[2], vb1[2], vb2[2];
    vb1[0] = pb1; vb2[0] = pb2;

    const int aOff0 = m * AST + kcStart * 32 + qs;
    va1[0] = *(const halfx8*)(pA1 + aOff0);
    va2[0] = *(const halfx8*)(pA2 + aOff0);

    #pragma unroll
    for (int i = 0; i < KCNT; ++i) {
        const int cur = i & 1, nxt = cur ^ 1;
        if (i + 1 < KCNT) {
            const size_t fOff = ((size_t)(fbBase + i + 1) * 64 + lane) * 8;
            vb1[nxt] = *(const halfx8*)(B1g + fOff);
            vb2[nxt] = *(const halfx8*)(B2g + fOff);
            const int aOff = m * AST + (kcStart + i + 1) * 32 + qs;
            va1[nxt] = *(const halfx8*)(pA1 + aOff);
            va2[nxt] = *(const halfx8*)(pA2 + aOff);
        }
        acc1 = __builtin_amdgcn_mfma_f32_16x16x32_f16(va1[cur], vb1[cur], acc1, 0, 0, 0);
        acc2 = __builtin_amdgcn_mfma_f32_16x16x32_f16(va1[cur], vb2[cur], acc2, 0, 0, 0);
        acc2 = __builtin_amdgcn_mfma_f32_16x16x32_f16(va2[cur], vb1[cur], acc2, 0, 0, 0);
    }
    acc1o = acc1; acc2o = acc2;
}

// Un-preloaded variant for L0 (B lives in the LDS cW0 cache; ~120cy latency,
// nothing worth preloading).
template<int KCNT>
__device__ __forceinline__ void mfma_run(const _Float16* __restrict__ pA1,
                                         const _Float16* __restrict__ pA2,
                                         const _Float16* __restrict__ B1g,
                                         const _Float16* __restrict__ B2g,
                                         int fbBase, int kcStart, int lane,
                                         floatx4& acc1o, floatx4& acc2o)
{
    const int m = lane & 15, q = lane >> 4;
    const int qs = (q ^ ((m >> 2) & 3)) * 8;
    floatx4 acc1 = (floatx4)0.0f, acc2 = (floatx4)0.0f;
    halfx8 va1[2], va2[2], vb1[2], vb2[2];

    const int aOff0 = m * AST + kcStart * 32 + qs;
    const size_t fOff0 = ((size_t)fbBase * 64 + lane) * 8;
    vb1[0] = *(const halfx8*)(B1g + fOff0);
    vb2[0] = *(const halfx8*)(B2g + fOff0);
    va1[0] = *(const halfx8*)(pA1 + aOff0);
    va2[0] = *(const halfx8*)(pA2 + aOff0);

    #pragma unroll
    for (int i = 0; i < KCNT; ++i) {
        const int cur = i & 1, nxt = cur ^ 1;
        if (i + 1 < KCNT) {
            const size_t fOff = ((size_t)(fbBase + i + 1) * 64 + lane) * 8;
            vb1[nxt] = *(const halfx8*)(B1g + fOff);
            vb2[nxt] = *(const halfx8*)(B2g + fOff);
            const int aOff = m * AST + (kcStart + i + 1) * 32 + qs;
            va1[nxt] = *(const halfx8*)(pA1 + aOff);
            va2[nxt] = *(const halfx8*)(pA2 + aOff);
        }
        acc1 = __builtin_amdgcn_mfma_f32_16x16x32_f16(va1[cur], vb1[cur], acc1, 0, 0, 0);
        acc2 = __builtin_amdgcn_mfma_f32_16x16x32_f16(va1[cur], vb2[cur], acc2, 0, 0, 0);
        acc2 = __builtin_amdgcn_mfma_f32_16x16x32_f16(va2[cur], vb1[cur], acc2, 0, 0, 0);
    }
    acc1o = acc1; acc2o = acc2;
}

// Hidden-layer epilogue with swizzled store column.
__device__ __forceinline__ void hidden_epi(floatx4 a1, floatx4 a2,
                                           const float* __restrict__ bias,
                                           _Float16* __restrict__ o1,
                                           _Float16* __restrict__ o2,
                                           int w, int lane)
{
    const int m = lane & 15, q = lane >> 4;
    const int col = (w << 4) + m;
    const int colS = col ^ (q << 3);   // swizzled storage column (row>>2 == q)
    const float bb = bias[col];
    #pragma unroll
    for (int v = 0; v < 4; ++v) {
        float val = fast_tanh(a1[v] + a2[v] * (1.0f / 4096.0f) + bb);
        _Float16 h1 = (_Float16)val;
        _Float16 h2 = (_Float16)((val - (float)h1) * 4096.0f);
        const int idx = (q * 4 + v) * AST + colS;   // m89-verified C/D mapping
        o1[idx] = h1;
        o2[idx] = h2;
    }
}

// R9 = R7 (4315us, best verified) + (1) sA bank-conflict swizzle, (2) chunk-0
// B register preload for L1/L2/L3 issued before the prior barrier. No staged
// LDS B (R8's race + drain), no persistent state beyond 8 VGPRs across one
// barrier (R1-R4: 64-VGPR cap is immovable).
__global__ void __launch_bounds__(NTHREADS)
ode_kernel(const float* __restrict__ ts, const float* __restrict__ y0,
           const float* __restrict__ b0, const float* __restrict__ b1,
           const float* __restrict__ b2, const float* __restrict__ b3,
           const _Float16* __restrict__ ws, float* __restrict__ out)
{
    // parity-0 / parity-1 A-split buffers
    __shared__ __align__(16) _Float16 sA1[2][TB * AST];
    __shared__ __align__(16) _Float16 sA2[2][TB * AST];
    __shared__ __align__(16) _Float16 cW0[32768];   // W0 plane1 [0,16384) + plane2 [16384,32768)
    __shared__ __align__(16) float sK[5][TB * DIM];
    __shared__ __align__(16) float sY[TB * DIM];
    __shared__ __align__(16) float sP[4][TB * SPS];
    __shared__ __align__(16) float sBias[832];

    const int tid  = threadIdx.x;
    const int lane = tid & 63;
    const int w    = tid >> 6;
    const long base = (long)blockIdx.x * (TB * DIM);
    const int c = tid & 63;       // element column (feature)
    const int r = tid >> 6;       // element row (batch row within tile)
    const int nt = w & 3, kg = w >> 2;
    const int cS = c ^ (((r >> 2) & 3) << 3);   // swizzled sA column for (r,c)

    // Stage the W0 cache (ws[L0S1..] holds plane1+plane2 contiguously).
    #pragma unroll
    for (int i = 0; i < 4; ++i)
        ((halfx8*)cW0)[tid + i * NTHREADS] = ((const halfx8*)(ws + L0S1))[tid + i * NTHREADS];

    if (tid < 832) {
        float v;
        if (tid < 256)      v = b0[tid];
        else if (tid < 512) v = b1[tid - 256];
        else if (tid < 768) v = b2[tid - 512];
        else                v = b3[tid - 768];
        sBias[tid] = v;
    }
    {
        float v = y0[base + tid];
        sY[tid] = v;
        __builtin_nontemporal_store(v, &out[base + tid]);
        _Float16 h1 = (_Float16)v;
        _Float16 h2 = (_Float16)((v - (float)h1) * 4096.0f);
        sA1[0][r * AST + cS] = h1;
        sA2[0][r * AST + cS] = h2;
    }
    __syncthreads();

    const int r68 = r * SPS + c;   // padded sP index for the elementwise phase

    for (int t = 0; t < NTIME - 1; ++t) {
        const float h = ts[t + 1] - ts[t];

        #pragma unroll 1
        for (int s = 0; s < 6; ++s) {
            floatx4 a1, a2;
            // L0: parity 0 -> parity 1; B from LDS cache
            mfma_run<2>(sA1[0], sA2[0], cW0, cW0 + 16384, w * 2, 0, lane, a1, a2);
            halfx8 pb1a, pb1b;                       // preload L1 chunk 0
            load_b(ws + L1S1, ws + L1S2, w * 8, lane, pb1a, pb1b);
            hidden_epi(a1, a2, sBias + 0, sA1[1], sA2[1], w, lane);
            bar_lds();
            // L1: parity 1 -> parity 0 (chunk 0 preloaded across the barrier)
            mfma_run_pre<8>(sA1[1], sA2[1], ws + L1S1, ws + L1S2, w * 8, 0, lane,
                            pb1a, pb1b, a1, a2);
            halfx8 pb2a, pb2b;                       // preload L2 chunk 0
            load_b(ws + L2S1, ws + L2S2, w * 8, lane, pb2a, pb2b);
            hidden_epi(a1, a2, sBias + 256, sA1[0], sA2[0], w, lane);
            bar_lds();
            // L2: parity 0 -> parity 1
            mfma_run_pre<8>(sA1[0], sA2[0], ws + L2S1, ws + L2S2, w * 8, 0, lane,
                            pb2a, pb2b, a1, a2);
            halfx8 pb3a, pb3b;                       // preload L3 chunk kg*2
            load_b(ws + L3S1, ws + L3S2, nt * 8 + kg * 2, lane, pb3a, pb3b);
            hidden_epi(a1, a2, sBias + 512, sA1[1], sA2[1], w, lane);
            bar_lds();
            // L3: parity 1 -> partials in sP (4-way K-split across wave groups)
            {
                mfma_run_pre<2>(sA1[1], sA2[1], ws + L3S1, ws + L3S2,
                                nt * 8 + kg * 2, kg * 2, lane, pb3a, pb3b, a1, a2);
                const int m = lane & 15, q = lane >> 4;
                #pragma unroll
                for (int v = 0; v < 4; ++v)
                    sP[kg][(q * 4 + v) * SPS + nt * 16 + m]
                        = a1[v] + a2[v] * (1.0f / 4096.0f);
            }
            bar_lds();

            // element-wise: reduce partials -> k_s, form next stage input (or y update)
            float kv = sP[0][r68] + sP[1][r68] + sP[2][r68] + sP[3][r68]
                     + sBias[768 + c];
            float v;
            if (s == 0) {
                sK[0][tid] = kv;
                v = fmaf(h, A21 * kv, sY[tid]);
            } else if (s == 1) {
                sK[1][tid] = kv;
                v = fmaf(h, fmaf(A31, sK[0][tid], A32 * kv), sY[tid]);
            } else if (s == 2) {
                sK[2][tid] = kv;
                float sum = A41 * sK[0][tid] + A42 * sK[1][tid] + A43 * kv;
                v = fmaf(h, sum, sY[tid]);
            } else if (s == 3) {
                sK[3][tid] = kv;
                float sum = A51 * sK[0][tid] + A52 * sK[1][tid] + A53 * sK[2][tid] + A54 * kv;
                v = fmaf(h, sum, sY[tid]);
            } else if (s == 4) {
                sK[4][tid] = kv;
                float sum = A61 * sK[0][tid] + A62 * sK[1][tid] + A63 * sK[2][tid]
                          + A64 * sK[3][tid] + A65 * kv;
                v = fmaf(h, sum, sY[tid]);
            } else {
                float sum = B1 * sK[0][tid] + B2 * sK[1][tid] + B3 * sK[2][tid]
                          + B4 * sK[3][tid] + B5 * sK[4][tid] + B6 * kv;
                v = fmaf(h, sum, sY[tid]);
                sY[tid] = v;
                __builtin_nontemporal_store(v, &out[(long)(t + 1) * (BATCH * DIM) + base + tid]);
            }
            _Float16 h1 = (_Float16)v;
            _Float16 h2 = (_Float16)((v - (float)h1) * 4096.0f);
            sA1[0][r * AST + cS] = h1;
            sA2[0][r * AST + cS] = h2;
            bar_lds();
        }
    }
}

extern "C" void kernel_launch(void* const* d_in, const int* in_sizes, int n_in,
                              void* d_out, int out_size, void* d_ws, size_t ws_size,
                              hipStream_t stream) {
    (void)in_sizes; (void)n_in; (void)ws_size; (void)out_size;
    const float* ts = (const float*)d_in[0];
    const float* y0 = (const float*)d_in[1];
    const float* W0 = (const float*)d_in[2];
    const float* b0 = (const float*)d_in[3];
    const float* W1 = (const float*)d_in[4];
    const float* b1 = (const float*)d_in[5];
    const float* W2 = (const float*)d_in[6];
    const float* b2 = (const float*)d_in[7];
    const float* W3 = (const float*)d_in[8];
    const float* b3 = (const float*)d_in[9];
    _Float16* ws = (_Float16*)d_ws;
    float* out = (float*)d_out;

    hipLaunchKernelGGL(pack_weights, dim3(640), dim3(256), 0, stream, W0, W1, W2, W3, ws);
    hipLaunchKernelGGL(ode_kernel, dim3(BATCH / TB), dim3(NTHREADS), 0, stream,
                       ts, y0, b0, b1, b2, b3, ws, out);
}